// Round 1
// baseline (70.921 us; speedup 1.0000x reference)
//
#include <hip/hip_runtime.h>

// Permute: out = X @ Q where Q is a one-hot permutation matrix.
// (X@Q)[b][j] = X[b][inv[j]] with inv = perm^{-1}, recovered by scanning Q.

#define FEATURES 4096
#define BATCH 8192

// Kernel 1: scan Q (FEATURES x FEATURES, row-major) for nonzeros.
// Q[i][j] != 0  =>  perm[i] == j  =>  inv[j] = i.
// Exactly one nonzero per column => every inv[j] written exactly once.
__global__ __launch_bounds__(256) void build_inv_kernel(
    const float4* __restrict__ Q4, int* __restrict__ inv, int total4) {
    int idx = blockIdx.x * blockDim.x + threadIdx.x;
    int stride = gridDim.x * blockDim.x;
    for (int i = idx; i < total4; i += stride) {
        float4 v = Q4[i];
        // Fast path: permutation matrix is mostly zeros; skip whole quad.
        if (v.x == 0.f && v.y == 0.f && v.z == 0.f && v.w == 0.f) continue;
        int base = i << 2;                 // flat element index
        int row  = base >> 12;             // / FEATURES (4096)
        int col  = base & (FEATURES - 1);  // % FEATURES
        if (v.x != 0.f) inv[col + 0] = row;
        if (v.y != 0.f) inv[col + 1] = row;
        if (v.z != 0.f) inv[col + 2] = row;
        if (v.w != 0.f) inv[col + 3] = row;
    }
}

// Kernel 2: per block, stage one 16 KB row of X in LDS, then write the
// permuted row with coalesced float4 stores (gather happens in LDS).
__global__ __launch_bounds__(256) void permute_gather_kernel(
    const float* __restrict__ X, const int* __restrict__ inv,
    float* __restrict__ out) {
    __shared__ float row[FEATURES];
    const int b = blockIdx.x;
    const float4* __restrict__ x4 = (const float4*)(X + (size_t)b * FEATURES);

    // Coalesced load of the row into LDS (16 B/lane).
    for (int i = threadIdx.x; i < FEATURES / 4; i += 256) {
        float4 v = x4[i];
        row[i * 4 + 0] = v.x;
        row[i * 4 + 1] = v.y;
        row[i * 4 + 2] = v.z;
        row[i * 4 + 3] = v.w;
    }
    __syncthreads();

    float4* __restrict__ out4 = (float4*)(out + (size_t)b * FEATURES);
    const int4* __restrict__ inv4 = (const int4*)inv;  // L2-resident (16 KB)
    for (int i = threadIdx.x; i < FEATURES / 4; i += 256) {
        int4 idx = inv4[i];
        float4 v;
        v.x = row[idx.x];
        v.y = row[idx.y];
        v.z = row[idx.z];
        v.w = row[idx.w];
        out4[i] = v;  // coalesced 16 B/lane store
    }
}

extern "C" void kernel_launch(void* const* d_in, const int* in_sizes, int n_in,
                              void* d_out, int out_size, void* d_ws, size_t ws_size,
                              hipStream_t stream) {
    const float* X = (const float*)d_in[0];
    const float* Q = (const float*)d_in[1];
    float* out = (float*)d_out;
    int* inv = (int*)d_ws;  // 4096 ints = 16 KB scratch

    const int total4 = (FEATURES * FEATURES) / 4;  // 4M float4 quads
    build_inv_kernel<<<2048, 256, 0, stream>>>((const float4*)Q, inv, total4);
    permute_gather_kernel<<<BATCH, 256, 0, stream>>>(X, inv, out);
}